// Round 7
// baseline (3510.223 us; speedup 1.0000x reference)
//
#include <hip/hip_runtime.h>
#include <stdint.h>
#include <stddef.h>

#define B_ 64
#define L_ 200
#define F_ 512
#define H_ 512
#define A_ 512
#define E_ 512
#define V_ 50257
#define T_ 21
#define D_ 1024
#define NBLK_LOG 786   /* ceil(V/64) */
#define BH (B_ * H_)
#define BD (B_ * D_)
#define NROW 1280      /* 20 planes x 64 batch */

typedef __attribute__((ext_vector_type(8))) short short8;
typedef __attribute__((ext_vector_type(4))) float f32x4;

__device__ __forceinline__ unsigned short f2b(float f) {
  unsigned int u = __builtin_bit_cast(unsigned int, f);
  u += 0x7FFFu + ((u >> 16) & 1u);
  return (unsigned short)(u >> 16);
}
__device__ __forceinline__ float b2f(unsigned short s) {
  unsigned int u = ((unsigned int)s) << 16;
  return __builtin_bit_cast(float, u);
}
__device__ __forceinline__ f32x4 mfma16(short8 a, short8 b, f32x4 c) {
  return __builtin_amdgcn_mfma_f32_16x16x32_bf16(a, b, c, 0, 0, 0);
}
// fragment-ordered layouts
__device__ __forceinline__ int hsoff(int b, int j) {  // (64 x 512) plane
  return (((b >> 4) * 16 + (j >> 5)) * 64 + (((j >> 3) & 3) * 16 + (b & 15))) * 8 + (j & 7);
}
__device__ __forceinline__ int xoff(int b, int k) {   // (64 x 1024) plane
  return (((b >> 4) * 32 + (k >> 5)) * 64 + (((k >> 3) & 3) * 16 + (b & 15))) * 8 + (k & 7);
}

/* ---------------- setup kernels ---------------- */

__global__ void k_cvt(const float* __restrict__ src, unsigned short* __restrict__ dst, int n4) {
  int i = blockIdx.x * blockDim.x + threadIdx.x;
  int stride = gridDim.x * blockDim.x;
  const float4* s4 = (const float4*)src;
  ushort4* d4 = (ushort4*)dst;
  for (; i < n4; i += stride) {
    float4 v = s4[i];
    ushort4 o;
    o.x = f2b(v.x); o.y = f2b(v.y); o.z = f2b(v.z); o.w = f2b(v.w);
    d4[i] = o;
  }
}

// W f32 (R,K) row-major -> fragment-ordered bf16 ; grid R/16 blocks
__global__ void k_wfrag(const float* __restrict__ src, unsigned short* __restrict__ dst, int K) {
  int rt = blockIdx.x;
  int r15 = threadIdx.x & 15;
  int row = rt * 16 + r15;
  int nch = K >> 3;
  int kpw = K >> 5;
  for (int kc = threadIdx.x >> 4; kc < nch; kc += 16) {
    const float4* s = (const float4*)(src + (size_t)row * K + kc * 8);
    float4 x = s[0], y = s[1];
    short8 o;
    o[0] = f2b(x.x); o[1] = f2b(x.y); o[2] = f2b(x.z); o[3] = f2b(x.w);
    o[4] = f2b(y.x); o[5] = f2b(y.y); o[6] = f2b(y.z); o[7] = f2b(y.w);
    *(short8*)(dst + ((size_t)(rt * kpw + (kc >> 2)) * 64 + ((kc & 3) * 16 + r15)) * 8) = o;
  }
}

// src f32 (R,C) -> dst bf16 (C,R); grid (C/64, R/64), 256 thr
__global__ void k_transcvt(const float* __restrict__ src, unsigned short* __restrict__ dst, int R, int C) {
  __shared__ float tile[64][65];
  int cb = blockIdx.x * 64, rb = blockIdx.y * 64;
  int tx = threadIdx.x & 63, ty = threadIdx.x >> 6;
#pragma unroll
  for (int i = 0; i < 16; ++i) {
    int r = ty * 16 + i;
    tile[r][tx] = src[(size_t)(rb + r) * C + cb + tx];
  }
  __syncthreads();
#pragma unroll
  for (int i = 0; i < 16; ++i) {
    int c = ty * 16 + i;
    dst[(size_t)(cb + c) * R + rb + tx] = f2b(tile[tx][c]);
  }
}

// src f32 (R,C) -> dst f32 (C,R); grid (C/64, R/64)
__global__ void k_trans32(const float* __restrict__ src, float* __restrict__ dst, int R, int C) {
  __shared__ float tile[64][65];
  int cb = blockIdx.x * 64, rb = blockIdx.y * 64;
  int tx = threadIdx.x & 63, ty = threadIdx.x >> 6;
#pragma unroll
  for (int i = 0; i < 16; ++i) {
    int r = ty * 16 + i;
    tile[r][tx] = src[(size_t)(rb + r) * C + cb + tx];
  }
  __syncthreads();
#pragma unroll
  for (int i = 0; i < 16; ++i) {
    int c = ty * 16 + i;
    dst[(size_t)(cb + c) * R + rb + tx] = tile[tx][c];
  }
}

// dih (B,H) f32 -> hs fragment layout (plane 0) ; grid 64
__global__ void k_hs0(const float* __restrict__ src, unsigned short* __restrict__ hs) {
  int b = blockIdx.x;
  for (int j = threadIdx.x; j < H_; j += 256)
    hs[hsoff(b, j)] = f2b(src[(size_t)b * H_ + j]);
}

// all-step embeddings -> x-plane cols 0..511 ; grid (64, 20), 64 thr
__global__ void k_embAll(const int* __restrict__ ref, const float* __restrict__ et,
                         unsigned short* __restrict__ xAll) {
  int b = blockIdx.x, tp = blockIdx.y;
  int word = ref[b * T_ + tp];
  const float* er = et + (size_t)word * E_;
  unsigned short* dst = xAll + (size_t)tp * BD;
  int c = threadIdx.x;  // 0..63
  const float4* s = (const float4*)(er + c * 8);
  float4 x = s[0], y = s[1];
  short8 o;
  o[0] = f2b(x.x); o[1] = f2b(x.y); o[2] = f2b(x.z); o[3] = f2b(x.w);
  o[4] = f2b(y.x); o[5] = f2b(y.y); o[6] = f2b(y.z); o[7] = f2b(y.w);
  *(short8*)(dst + xoff(b, c * 8)) = o;
}

// ep2[(b*512 + a)*200 + l] = sum_f encb[(b,l)][f] * WaTb[a][f] ; grid 200 blocks
__global__ __launch_bounds__(256, 2) void k_encproj2(const unsigned short* __restrict__ encb,
                                                     const unsigned short* __restrict__ WaTb,
                                                     unsigned short* __restrict__ ep2) {
  __shared__ unsigned short al[32768];
  int tid = threadIdx.x;
  size_t rowbase = (size_t)blockIdx.x * 64;
  for (int idx = tid; idx < 4096; idx += 256) {
    int row = idx >> 6, seg = idx & 63;
    unsigned char* dp = (unsigned char*)al + row * 1024 + ((seg * 16) ^ ((row & 7) << 4));
    *(short8*)dp = *(const short8*)(encb + (rowbase + row) * F_ + seg * 8);
  }
  __syncthreads();
  int w = tid >> 6, lane = tid & 63, ln15 = lane & 15, g = lane >> 4;
  int sw = (ln15 & 7) << 4;
  const unsigned char* alb = (const unsigned char*)al;
  int mrow = w * 16 + ln15;
  for (int nt = 0; nt < 32; ++nt) {
    f32x4 acc = {0.f, 0.f, 0.f, 0.f};
    const unsigned short* brow = WaTb + (size_t)(nt * 16 + ln15) * F_ + 8 * g;
#pragma unroll 4
    for (int kk = 0; kk < 16; ++kk) {
      short8 bf = *(const short8*)(brow + kk * 32);
      short8 af = *(const short8*)(alb + mrow * 1024 + ((kk * 64 + 16 * g) ^ sw));
      acc = mfma16(af, bf, acc);
    }
    int aa = nt * 16 + ln15;
#pragma unroll
    for (int r = 0; r < 4; ++r) {
      int mm = (int)rowbase + w * 16 + 4 * g + r;
      int bb = mm / 200;
      int ll = mm - bb * 200;
      ep2[((size_t)bb * 512 + aa) * 200 + ll] = f2b(acc[r]);
    }
  }
}

// out[:,0,:] = 0 ; grid (50, 64)
__global__ void k_zero0(float* __restrict__ out) {
  int b = blockIdx.y;
  float* o = out + (size_t)b * T_ * V_;
  int v0 = blockIdx.x * 1024 + threadIdx.x;
#pragma unroll
  for (int i = 0; i < 4; ++i) { int v = v0 + i * 256; if (v < V_) o[v] = 0.f; }
}

/* ---------------- per-step: attention (no shuffles in GEMVs) ---------------- */

__global__ __launch_bounds__(256) void k_attn(const float* __restrict__ mask,
                                              const unsigned short* __restrict__ encb,
                                              const unsigned short* __restrict__ ep2,
                                              const unsigned short* __restrict__ Wahb,
                                              const float* __restrict__ vatt,
                                              const float* __restrict__ hT,
                                              unsigned short* __restrict__ xplane) {
  __shared__ float Sh[H_];
  __shared__ float Shw[A_];
  __shared__ float Ssc[L_];
  __shared__ float Sctx[F_];
  int b = blockIdx.x;
  int tid = threadIdx.x;
  for (int k = tid; k < H_; k += 256) Sh[k] = hT[(size_t)k * B_ + b];
  __syncthreads();
  // hw[a] = sum_k Wah[k][a] * h[k] ; thread-per-a, k-serial, lanes coalesced over a
#pragma unroll
  for (int a0 = 0; a0 < 2; ++a0) {
    int a = tid + a0 * 256;
    const unsigned short* wa = Wahb + a;
    float acc = 0.f;
#pragma unroll 8
    for (int k = 0; k < 512; ++k) acc = fmaf(b2f(wa[(size_t)k * 512]), Sh[k], acc);
    Shw[a] = acc;
  }
  __syncthreads();
  // score[l] = sum_a tanh(ep2[b,a,l] + hw[a]) * v[a] ; thread-per-l, a-serial
  if (tid < L_) {
    const unsigned short* e = ep2 + ((size_t)b * 512) * 200 + tid;
    float acc = 0.f;
#pragma unroll 4
    for (int a = 0; a < 512; ++a) {
      float x = b2f(e[(size_t)a * 200]) + Shw[a];
      float e2 = __expf(x + x);
      acc = fmaf(1.f - 2.f / (e2 + 1.f), vatt[a], acc);
    }
    float mk = mask[b * L_ + tid];
    Ssc[tid] = (mk > 0.f) ? acc : -1e9f;
  }
  __syncthreads();
  if (tid < 64) {
    float m = -1e30f;
    for (int l = tid; l < L_; l += 64) m = fmaxf(m, Ssc[l]);
    for (int o = 1; o < 64; o <<= 1) m = fmaxf(m, __shfl_xor(m, o));
    float s = 0.f;
    for (int l = tid; l < L_; l += 64) s += __expf(Ssc[l] - m);
    for (int o = 1; o < 64; o <<= 1) s += __shfl_xor(s, o);
    float inv = 1.f / s;
    for (int l = tid; l < L_; l += 64) Ssc[l] = __expf(Ssc[l] - m) * inv;
  }
  __syncthreads();
  // ctx[f] = sum_l attn[l] * encb[b,l,f] ; thread-per-f, l-serial
#pragma unroll
  for (int f0 = 0; f0 < 2; ++f0) {
    int f = tid + f0 * 256;
    const unsigned short* e = encb + ((size_t)b * L_) * F_ + f;
    float acc = 0.f;
#pragma unroll 4
    for (int l = 0; l < L_; ++l) acc = fmaf(Ssc[l], b2f(e[(size_t)l * F_]), acc);
    Sctx[f] = acc;
  }
  __syncthreads();
  if (tid < 64) {
    short8 o;
#pragma unroll
    for (int j = 0; j < 8; ++j) o[j] = f2b(Sctx[tid * 8 + j]);
    *(short8*)(xplane + xoff(b, E_ + tid * 8)) = o;
  }
}

/* ---------------- per-step: GRU via MFMA (frag weights) ---------------- */

__global__ __launch_bounds__(256) void k_gruM(const unsigned short* __restrict__ Wfih,
                                              const unsigned short* __restrict__ Wfhh,
                                              const float* __restrict__ bih,
                                              const float* __restrict__ bhh,
                                              const unsigned short* __restrict__ xplane,
                                              const unsigned short* __restrict__ hsold,
                                              const float* __restrict__ hTold,
                                              unsigned short* __restrict__ hsnew,
                                              float* __restrict__ hTnew) {
  int bx = blockIdx.x;
  int w = threadIdx.x >> 6, lane = threadIdx.x & 63;
  int ln15 = lane & 15, g = lane >> 4;
  f32x4 z4 = {0.f, 0.f, 0.f, 0.f};
  f32x4 aIr = z4, aIz = z4, aIn = z4, aHr = z4, aHz = z4, aHn = z4;
  {
#pragma unroll 2
    for (int kk = 0; kk < 32; ++kk) {
      short8 xv = *(const short8*)(xplane + (((size_t)w * 32 + kk) * 64 + lane) * 8);
      aIr = mfma16(*(const short8*)(Wfih + (((size_t)(0 * 32 + bx) * 32 + kk) * 64 + lane) * 8), xv, aIr);
      aIz = mfma16(*(const short8*)(Wfih + (((size_t)(32 + bx) * 32 + kk) * 64 + lane) * 8), xv, aIz);
      aIn = mfma16(*(const short8*)(Wfih + (((size_t)(64 + bx) * 32 + kk) * 64 + lane) * 8), xv, aIn);
    }
  }
  {
#pragma unroll 2
    for (int kk = 0; kk < 16; ++kk) {
      short8 hv = *(const short8*)(hsold + (((size_t)w * 16 + kk) * 64 + lane) * 8);
      aHr = mfma16(*(const short8*)(Wfhh + (((size_t)(0 * 32 + bx) * 16 + kk) * 64 + lane) * 8), hv, aHr);
      aHz = mfma16(*(const short8*)(Wfhh + (((size_t)(32 + bx) * 16 + kk) * 64 + lane) * 8), hv, aHz);
      aHn = mfma16(*(const short8*)(Wfhh + (((size_t)(64 + bx) * 16 + kk) * 64 + lane) * 8), hv, aHn);
    }
  }
  int jb = bx * 16;
#pragma unroll
  for (int r = 0; r < 4; ++r) {
    int j = jb + 4 * g + r;
    int b = w * 16 + ln15;
    float ir = aIr[r] + bih[j];
    float iz = aIz[r] + bih[512 + j];
    float in_ = aIn[r] + bih[1024 + j];
    float hrv = aHr[r] + bhh[j];
    float hzv = aHz[r] + bhh[512 + j];
    float hnv = aHn[r] + bhh[1024 + j];
    float rg = 1.f / (1.f + __expf(-(ir + hrv)));
    float zg = 1.f / (1.f + __expf(-(iz + hzv)));
    float e2 = __expf(2.f * (in_ + rg * hnv));
    float ng = 1.f - 2.f / (e2 + 1.f);
    float ho = hTold[(size_t)j * B_ + b];
    float hv = (1.f - zg) * ng + zg * ho;
    hTnew[(size_t)j * B_ + b] = hv;
    hsnew[hsoff(b, j)] = f2b(hv);
  }
}

/* ---------------- logits: two-pass GEMM, t-split grid ---------------- */

__global__ __launch_bounds__(256) void k_blog(const unsigned short* __restrict__ Wb,
                                              const float* __restrict__ bout,
                                              const unsigned short* __restrict__ hsAll,
                                              float* __restrict__ pm, float* __restrict__ ps,
                                              const float* __restrict__ lse,
                                              float* __restrict__ out, int pass) {
  __shared__ float tile[64][68];
  __shared__ float redm[64][4], reds[64][4];
  int tid = threadIdx.x;
  int w = tid >> 6, lane = tid & 63, ln15 = lane & 15, g = lane >> 4;
  int vcol = blockIdx.x * 64 + w * 16 + ln15;
  bool vok = vcol < V_;
  int vr = vok ? vcol : (V_ - 1);
  const unsigned short* brow = Wb + (size_t)vr * H_ + 8 * g;
  short8 wb[16];
#pragma unroll
  for (int kk = 0; kk < 16; ++kk) wb[kk] = *(const short8*)(brow + kk * 32);
  float bo = bout[vr];
  int row = tid >> 2, seg = tid & 3;
  int t0 = blockIdx.y * 4;

  for (int t = t0; t < t0 + 4; ++t) {
    const unsigned short* hp = hsAll + (size_t)(t + 1) * BH;
#pragma unroll
    for (int mp = 0; mp < 2; ++mp) {
      f32x4 z4 = {0.f, 0.f, 0.f, 0.f};
      f32x4 acc0 = z4, acc1 = z4;
#pragma unroll
      for (int kk = 0; kk < 16; ++kk) {
        short8 a0 = *(const short8*)(hp + (((mp * 2 + 0) * 16 + kk) * 64 + lane) * 8);
        short8 a1 = *(const short8*)(hp + (((mp * 2 + 1) * 16 + kk) * 64 + lane) * 8);
        acc0 = mfma16(a0, wb[kk], acc0);
        acc1 = mfma16(a1, wb[kk], acc1);
      }
#pragma unroll
      for (int r = 0; r < 4; ++r) {
        int bi0 = (mp * 2 + 0) * 16 + 4 * g + r;
        int bi1 = (mp * 2 + 1) * 16 + 4 * g + r;
        tile[bi0][w * 16 + ln15] = vok ? acc0[r] + bo : -1e30f;
        tile[bi1][w * 16 + ln15] = vok ? acc1[r] + bo : -1e30f;
      }
    }
    __syncthreads();
    if (pass == 0) {
      float m = -1e30f;
#pragma unroll
      for (int i = 0; i < 16; ++i) m = fmaxf(m, tile[row][seg * 16 + i]);
      float s = 0.f;
#pragma unroll
      for (int i = 0; i < 16; ++i) s += __expf(tile[row][seg * 16 + i] - m);
      redm[row][seg] = m; reds[row][seg] = s;
      __syncthreads();
      if (seg == 0) {
        float m0 = redm[row][0], m1 = redm[row][1], m2 = redm[row][2], m3 = redm[row][3];
        float m4 = fmaxf(fmaxf(m0, m1), fmaxf(m2, m3));
        float s4 = reds[row][0] * __expf(m0 - m4) + reds[row][1] * __expf(m1 - m4) +
                   reds[row][2] * __expf(m2 - m4) + reds[row][3] * __expf(m3 - m4);
        size_t rho = (size_t)t * 64 + row;
        pm[rho * NBLK_LOG + blockIdx.x] = m4;
        ps[rho * NBLK_LOG + blockIdx.x] = s4;
      }
      __syncthreads();
    } else {
      float Lv = lse[(size_t)t * 64 + row];
      int cb = blockIdx.x * 64 + seg * 16;
      float* orow = out + ((size_t)row * T_ + (t + 1)) * V_ + cb;
      if (cb + 16 <= V_) {
#pragma unroll
        for (int q = 0; q < 4; ++q) {
          float4 v;
          v.x = tile[row][seg * 16 + q * 4 + 0] - Lv;
          v.y = tile[row][seg * 16 + q * 4 + 1] - Lv;
          v.z = tile[row][seg * 16 + q * 4 + 2] - Lv;
          v.w = tile[row][seg * 16 + q * 4 + 3] - Lv;
          *(float4*)(orow + q * 4) = v;
        }
      } else {
        for (int i = 0; i < 16; ++i)
          if (cb + i < V_) orow[i] = tile[row][seg * 16 + i] - Lv;
      }
      __syncthreads();
    }
  }
}

// merge partials -> lse[rho] ; grid 1280
__global__ __launch_bounds__(256) void k_lse(const float* __restrict__ pm,
                                             const float* __restrict__ ps,
                                             float* __restrict__ lse) {
  int rho = blockIdx.x;
  int tid = threadIdx.x;
  float m = -1e30f, s = 0.f;
  for (int p = tid; p < NBLK_LOG; p += 256) {
    float pmv = pm[(size_t)rho * NBLK_LOG + p], psv = ps[(size_t)rho * NBLK_LOG + p];
    float nm = fmaxf(m, pmv);
    s = s * __expf(m - nm) + psv * __expf(pmv - nm);
    m = nm;
  }
  __shared__ float lm[256], ls[256];
  lm[tid] = m; ls[tid] = s;
  __syncthreads();
  for (int o = 128; o > 0; o >>= 1) {
    if (tid < o) {
      float m2 = lm[tid + o], s2 = ls[tid + o];
      float nm = fmaxf(lm[tid], m2);
      ls[tid] = ls[tid] * __expf(lm[tid] - nm) + s2 * __expf(m2 - nm);
      lm[tid] = nm;
    }
    __syncthreads();
  }
  if (tid == 0) lse[rho] = lm[0] + logf(ls[0]);
}

/* ---------------- host ---------------- */

extern "C" void kernel_launch(void* const* d_in, const int* in_sizes, int n_in,
                              void* d_out, int out_size, void* d_ws, size_t ws_size,
                              hipStream_t stream) {
  const float* enc   = (const float*)d_in[0];
  const float* dih   = (const float*)d_in[1];
  const float* mask  = (const float*)d_in[2];
  const float* et    = (const float*)d_in[4];
  const float* Wih   = (const float*)d_in[5];
  const float* Whh   = (const float*)d_in[6];
  const float* bih   = (const float*)d_in[7];
  const float* bhh   = (const float*)d_in[8];
  const float* Waenc = (const float*)d_in[9];
  const float* Wah   = (const float*)d_in[10];
  const float* vatt  = (const float*)d_in[11];
  const float* Wout  = (const float*)d_in[12];
  const float* bout  = (const float*)d_in[13];
  const int*   ref   = (const int*)d_in[14];
  float* out = (float*)d_out;

  char* w = (char*)d_ws;
  size_t o = 0;
  unsigned short* Wb    = (unsigned short*)(w + o); o += (size_t)V_ * H_ * 2;
  unsigned short* Wfih  = (unsigned short*)(w + o); o += (size_t)1536 * 1024 * 2;
  unsigned short* Wfhh  = (unsigned short*)(w + o); o += (size_t)1536 * 512 * 2;
  unsigned short* WaTb  = (unsigned short*)(w + o); o += (size_t)512 * 512 * 2;
  unsigned short* Wahb  = (unsigned short*)(w + o); o += (size_t)512 * 512 * 2;
  unsigned short* encb  = (unsigned short*)(w + o); o += (size_t)B_ * L_ * F_ * 2;
  unsigned short* ep2   = (unsigned short*)(w + o); o += (size_t)B_ * A_ * L_ * 2;
  unsigned short* xAll  = (unsigned short*)(w + o); o += (size_t)20 * BD * 2;
  unsigned short* hsAll = (unsigned short*)(w + o); o += (size_t)T_ * BH * 2;
  float* hTAll = (float*)(w + o); o += (size_t)T_ * BH * 4;
  float* pm  = (float*)(w + o); o += (size_t)NROW * NBLK_LOG * 4;
  float* ps  = (float*)(w + o); o += (size_t)NROW * NBLK_LOG * 4;
  float* lse = (float*)(w + o); o += (size_t)NROW * 4;

  k_cvt<<<4096, 256, 0, stream>>>(Wout, Wb, V_ * H_ / 4);
  k_cvt<<<2048, 256, 0, stream>>>(enc, encb, B_ * L_ * F_ / 4);
  k_cvt<<<256, 256, 0, stream>>>(Wah, Wahb, 512 * 512 / 4);
  k_wfrag<<<96, 256, 0, stream>>>(Wih, Wfih, 1024);
  k_wfrag<<<96, 256, 0, stream>>>(Whh, Wfhh, 512);
  k_transcvt<<<dim3(8, 8), 256, 0, stream>>>(Waenc, WaTb, 512, 512);
  k_trans32<<<dim3(8, 1), 256, 0, stream>>>(dih, hTAll, 64, 512);
  k_hs0<<<64, 256, 0, stream>>>(dih, hsAll);
  k_embAll<<<dim3(64, 20), 64, 0, stream>>>(ref, et, xAll);
  k_encproj2<<<200, 256, 0, stream>>>(encb, WaTb, ep2);
  k_zero0<<<dim3(50, 64), 256, 0, stream>>>(out);

  for (int t = 0; t < T_ - 1; ++t) {
    const float* hT_t = hTAll + (size_t)t * BH;
    float* hT_n = hTAll + (size_t)(t + 1) * BH;
    const unsigned short* hs_t = hsAll + (size_t)t * BH;
    unsigned short* hs_n = hsAll + (size_t)(t + 1) * BH;
    unsigned short* xp = xAll + (size_t)t * BD;
    k_attn<<<64, 256, 0, stream>>>(mask, encb, ep2, Wahb, vatt, hT_t, xp);
    k_gruM<<<32, 256, 0, stream>>>(Wfih, Wfhh, bih, bhh, xp, hs_t, hT_t, hs_n, hT_n);
  }
  k_blog<<<dim3(NBLK_LOG, 5), 256, 0, stream>>>(Wb, bout, hsAll, pm, ps, lse, out, 0);
  k_lse<<<1280, 256, 0, stream>>>(pm, ps, lse);
  k_blog<<<dim3(NBLK_LOG, 5), 256, 0, stream>>>(Wb, bout, hsAll, pm, ps, lse, out, 1);
}

// Round 8
// 1566.272 us; speedup vs baseline: 2.2411x; 2.2411x over previous
//
#include <hip/hip_runtime.h>
#include <stdint.h>
#include <stddef.h>

#define B_ 64
#define L_ 200
#define F_ 512
#define H_ 512
#define A_ 512
#define E_ 512
#define V_ 50257
#define T_ 21
#define D_ 1024
#define NBLK_LOG 786   /* ceil(V/64) */
#define BH (B_ * H_)
#define BD (B_ * D_)
#define NROW 1280      /* 20 planes x 64 batch */

typedef __attribute__((ext_vector_type(8))) short short8;
typedef __attribute__((ext_vector_type(4))) float f32x4;

__device__ __forceinline__ unsigned short f2b(float f) {
  unsigned int u = __builtin_bit_cast(unsigned int, f);
  u += 0x7FFFu + ((u >> 16) & 1u);
  return (unsigned short)(u >> 16);
}
__device__ __forceinline__ float b2f(unsigned short s) {
  unsigned int u = ((unsigned int)s) << 16;
  return __builtin_bit_cast(float, u);
}
__device__ __forceinline__ f32x4 mfma16(short8 a, short8 b, f32x4 c) {
  return __builtin_amdgcn_mfma_f32_16x16x32_bf16(a, b, c, 0, 0, 0);
}
// fragment-ordered layouts
__device__ __forceinline__ int hsoff(int b, int j) {  // (64 x 512) plane
  return (((b >> 4) * 16 + (j >> 5)) * 64 + (((j >> 3) & 3) * 16 + (b & 15))) * 8 + (j & 7);
}
__device__ __forceinline__ int xoff(int b, int k) {   // (64 x 1024) plane
  return (((b >> 4) * 32 + (k >> 5)) * 64 + (((k >> 3) & 3) * 16 + (b & 15))) * 8 + (k & 7);
}

/* ---------------- setup kernels ---------------- */

__global__ void k_cvt(const float* __restrict__ src, unsigned short* __restrict__ dst, int n4) {
  int i = blockIdx.x * blockDim.x + threadIdx.x;
  int stride = gridDim.x * blockDim.x;
  const float4* s4 = (const float4*)src;
  ushort4* d4 = (ushort4*)dst;
  for (; i < n4; i += stride) {
    float4 v = s4[i];
    ushort4 o;
    o.x = f2b(v.x); o.y = f2b(v.y); o.z = f2b(v.z); o.w = f2b(v.w);
    d4[i] = o;
  }
}

// W f32 (R,K) row-major -> fragment-ordered bf16 ; grid R/16 blocks
__global__ void k_wfrag(const float* __restrict__ src, unsigned short* __restrict__ dst, int K) {
  int rt = blockIdx.x;
  int r15 = threadIdx.x & 15;
  int row = rt * 16 + r15;
  int nch = K >> 3;
  int kpw = K >> 5;
  for (int kc = threadIdx.x >> 4; kc < nch; kc += 16) {
    const float4* s = (const float4*)(src + (size_t)row * K + kc * 8);
    float4 x = s[0], y = s[1];
    short8 o;
    o[0] = f2b(x.x); o[1] = f2b(x.y); o[2] = f2b(x.z); o[3] = f2b(x.w);
    o[4] = f2b(y.x); o[5] = f2b(y.y); o[6] = f2b(y.z); o[7] = f2b(y.w);
    *(short8*)(dst + ((size_t)(rt * kpw + (kc >> 2)) * 64 + ((kc & 3) * 16 + r15)) * 8) = o;
  }
}

// src f32 (R,C) -> dst bf16 (C,R); grid (C/64, R/64), 256 thr
__global__ void k_transcvt(const float* __restrict__ src, unsigned short* __restrict__ dst, int R, int C) {
  __shared__ float tile[64][65];
  int cb = blockIdx.x * 64, rb = blockIdx.y * 64;
  int tx = threadIdx.x & 63, ty = threadIdx.x >> 6;
#pragma unroll
  for (int i = 0; i < 16; ++i) {
    int r = ty * 16 + i;
    tile[r][tx] = src[(size_t)(rb + r) * C + cb + tx];
  }
  __syncthreads();
#pragma unroll
  for (int i = 0; i < 16; ++i) {
    int c = ty * 16 + i;
    dst[(size_t)(cb + c) * R + rb + tx] = f2b(tile[tx][c]);
  }
}

// src f32 (R,C) -> dst f32 (C,R); grid (C/64, R/64)
__global__ void k_trans32(const float* __restrict__ src, float* __restrict__ dst, int R, int C) {
  __shared__ float tile[64][65];
  int cb = blockIdx.x * 64, rb = blockIdx.y * 64;
  int tx = threadIdx.x & 63, ty = threadIdx.x >> 6;
#pragma unroll
  for (int i = 0; i < 16; ++i) {
    int r = ty * 16 + i;
    tile[r][tx] = src[(size_t)(rb + r) * C + cb + tx];
  }
  __syncthreads();
#pragma unroll
  for (int i = 0; i < 16; ++i) {
    int c = ty * 16 + i;
    dst[(size_t)(cb + c) * R + rb + tx] = tile[tx][c];
  }
}

// dih (B,H) f32 -> hs fragment layout (plane 0) ; grid 64
__global__ void k_hs0(const float* __restrict__ src, unsigned short* __restrict__ hs) {
  int b = blockIdx.x;
  for (int j = threadIdx.x; j < H_; j += 256)
    hs[hsoff(b, j)] = f2b(src[(size_t)b * H_ + j]);
}

// all-step embeddings -> x-plane cols 0..511 ; grid (64, 20), 64 thr
__global__ void k_embAll(const int* __restrict__ ref, const float* __restrict__ et,
                         unsigned short* __restrict__ xAll) {
  int b = blockIdx.x, tp = blockIdx.y;
  int word = ref[b * T_ + tp];
  const float* er = et + (size_t)word * E_;
  unsigned short* dst = xAll + (size_t)tp * BD;
  int c = threadIdx.x;  // 0..63
  const float4* s = (const float4*)(er + c * 8);
  float4 x = s[0], y = s[1];
  short8 o;
  o[0] = f2b(x.x); o[1] = f2b(x.y); o[2] = f2b(x.z); o[3] = f2b(x.w);
  o[4] = f2b(y.x); o[5] = f2b(y.y); o[6] = f2b(y.z); o[7] = f2b(y.w);
  *(short8*)(dst + xoff(b, c * 8)) = o;
}

// epb[(b*200+l)*512 + a] = sum_f encb[(b,l)][f] * WaTb[a][f] ; grid 200 blocks
__global__ __launch_bounds__(256, 2) void k_encproj2(const unsigned short* __restrict__ encb,
                                                     const unsigned short* __restrict__ WaTb,
                                                     unsigned short* __restrict__ epb) {
  __shared__ unsigned short al[32768];
  int tid = threadIdx.x;
  size_t rowbase = (size_t)blockIdx.x * 64;
  for (int idx = tid; idx < 4096; idx += 256) {
    int row = idx >> 6, seg = idx & 63;
    unsigned char* dp = (unsigned char*)al + row * 1024 + ((seg * 16) ^ ((row & 7) << 4));
    *(short8*)dp = *(const short8*)(encb + (rowbase + row) * F_ + seg * 8);
  }
  __syncthreads();
  int w = tid >> 6, lane = tid & 63, ln15 = lane & 15, g = lane >> 4;
  int sw = (ln15 & 7) << 4;
  const unsigned char* alb = (const unsigned char*)al;
  int mrow = w * 16 + ln15;
  for (int nt = 0; nt < 32; ++nt) {
    f32x4 acc = {0.f, 0.f, 0.f, 0.f};
    const unsigned short* brow = WaTb + (size_t)(nt * 16 + ln15) * F_ + 8 * g;
#pragma unroll 4
    for (int kk = 0; kk < 16; ++kk) {
      short8 bf = *(const short8*)(brow + kk * 32);
      short8 af = *(const short8*)(alb + mrow * 1024 + ((kk * 64 + 16 * g) ^ sw));
      acc = mfma16(af, bf, acc);
    }
#pragma unroll
    for (int r = 0; r < 4; ++r) {
      size_t m = rowbase + w * 16 + 4 * g + r;
      epb[m * A_ + nt * 16 + ln15] = f2b(acc[r]);
    }
  }
}

// out[:,0,:] = 0 ; grid (50, 64)
__global__ void k_zero0(float* __restrict__ out) {
  int b = blockIdx.y;
  float* o = out + (size_t)b * T_ * V_;
  int v0 = blockIdx.x * 1024 + threadIdx.x;
#pragma unroll
  for (int i = 0; i < 4; ++i) { int v = v0 + i * 256; if (v < V_) o[v] = 0.f; }
}

/* ---------------- per-step kernels (wide grids) ---------------- */

// hw[b][a] = sum_k h[b][k] * Wah[k][a] via MFMA ; grid 32 (a-tiles)
__global__ __launch_bounds__(256) void k_hw(const unsigned short* __restrict__ Wahf,
                                            const unsigned short* __restrict__ hs,
                                            float* __restrict__ hw) {
  int bx = blockIdx.x;
  int w = threadIdx.x >> 6, lane = threadIdx.x & 63;
  int ln15 = lane & 15, g = lane >> 4;
  f32x4 acc = {0.f, 0.f, 0.f, 0.f};
#pragma unroll 4
  for (int kk = 0; kk < 16; ++kk) {
    short8 av = *(const short8*)(Wahf + (((size_t)bx * 16 + kk) * 64 + lane) * 8);
    short8 hv = *(const short8*)(hs + (((size_t)w * 16 + kk) * 64 + lane) * 8);
    acc = mfma16(av, hv, acc);
  }
#pragma unroll
  for (int r = 0; r < 4; ++r) {
    int a = bx * 16 + 4 * g + r;
    int b = w * 16 + ln15;
    hw[(size_t)b * 512 + a] = acc[r];
  }
}

// scoreT[b*200+l] ; grid 200 blocks, 4 threads per (b,l) row
__global__ __launch_bounds__(256) void k_score(const unsigned short* __restrict__ epb,
                                               const float* __restrict__ hw,
                                               const float* __restrict__ vatt,
                                               const float* __restrict__ mask,
                                               float* __restrict__ scoreT) {
  __shared__ float SP[64][4];
  int tid = threadIdx.x;
  int rl = tid >> 2, aq = tid & 3;
  int row = blockIdx.x * 64 + rl;      // row = b*200 + l
  int b = row / 200;
  const unsigned short* e = epb + (size_t)row * 512 + aq * 128;
  const float* hp = hw + (size_t)b * 512 + aq * 128;
  const float* vp = vatt + aq * 128;
  float acc = 0.f;
#pragma unroll 4
  for (int i = 0; i < 16; ++i) {
    short8 ev = *(const short8*)(e + i * 8);
    const float* h8 = hp + i * 8;
    const float* v8 = vp + i * 8;
#pragma unroll
    for (int j = 0; j < 8; ++j) {
      float x = b2f((unsigned short)ev[j]) + h8[j];
      float e2 = __expf(x + x);
      acc = fmaf(1.f - 2.f / (e2 + 1.f), v8[j], acc);
    }
  }
  SP[rl][aq] = acc;
  __syncthreads();
  if (tid < 64) {
    float s = SP[tid][0] + SP[tid][1] + SP[tid][2] + SP[tid][3];
    int rw = blockIdx.x * 64 + tid;
    float mk = mask[rw];               // mask flat (b,l)
    scoreT[rw] = (mk > 0.f) ? s : -1e9f;
  }
}

// softmax (redundant per block) + ctx f-chunk ; grid (64 b, 4 fq), 256 thr
__global__ __launch_bounds__(256) void k_ctx(const float* __restrict__ scoreT,
                                             const unsigned short* __restrict__ encb,
                                             unsigned short* __restrict__ xplane) {
  __shared__ float sm[256];
  __shared__ float2 SC[64][4];
  __shared__ float ctxv[128];
  int b = blockIdx.x, fq = blockIdx.y;
  int tid = threadIdx.x;
  if (tid < 200) sm[tid] = scoreT[b * 200 + tid];
  __syncthreads();
  if (tid < 64) {
    float m = -1e30f;
    for (int l = tid; l < 200; l += 64) m = fmaxf(m, sm[l]);
    for (int o = 1; o < 64; o <<= 1) m = fmaxf(m, __shfl_xor(m, o));
    float s = 0.f;
    for (int l = tid; l < 200; l += 64) s += __expf(sm[l] - m);
    for (int o = 1; o < 64; o <<= 1) s += __shfl_xor(s, o);
    float inv = 1.f / s;
    for (int l = tid; l < 200; l += 64) sm[l] = __expf(sm[l] - m) * inv;
  }
  __syncthreads();
  int fp = tid & 63, lq = tid >> 6;
  const unsigned short* ep = encb + ((size_t)b * 200) * 512 + fq * 128 + fp * 2;
  float ax = 0.f, ay = 0.f;
#pragma unroll 2
  for (int i = 0; i < 50; ++i) {
    int l = lq * 50 + i;
    unsigned int u = *(const unsigned int*)(ep + (size_t)l * 512);
    float wgt = sm[l];
    ax = fmaf(wgt, b2f((unsigned short)(u & 0xffffu)), ax);
    ay = fmaf(wgt, b2f((unsigned short)(u >> 16)), ay);
  }
  SC[fp][lq] = make_float2(ax, ay);
  __syncthreads();
  if (tid < 64) {
    float sx = SC[tid][0].x + SC[tid][1].x + SC[tid][2].x + SC[tid][3].x;
    float sy = SC[tid][0].y + SC[tid][1].y + SC[tid][2].y + SC[tid][3].y;
    ctxv[tid * 2] = sx;
    ctxv[tid * 2 + 1] = sy;
  }
  __syncthreads();
  if (tid < 16) {
    short8 o;
#pragma unroll
    for (int j = 0; j < 8; ++j) o[j] = f2b(ctxv[tid * 8 + j]);
    *(short8*)(xplane + xoff(b, E_ + fq * 128 + tid * 8)) = o;
  }
}

// GRU cell, 16 j-cols per block ; grid 32
__global__ __launch_bounds__(256) void k_gruM(const unsigned short* __restrict__ Wfih,
                                              const unsigned short* __restrict__ Wfhh,
                                              const float* __restrict__ bih,
                                              const float* __restrict__ bhh,
                                              const unsigned short* __restrict__ xplane,
                                              const unsigned short* __restrict__ hsold,
                                              const float* __restrict__ hTold,
                                              unsigned short* __restrict__ hsnew,
                                              float* __restrict__ hTnew) {
  int bx = blockIdx.x;
  int w = threadIdx.x >> 6, lane = threadIdx.x & 63;
  int ln15 = lane & 15, g = lane >> 4;
  f32x4 z4 = {0.f, 0.f, 0.f, 0.f};
  f32x4 aIr = z4, aIz = z4, aIn = z4, aHr = z4, aHz = z4, aHn = z4;
  {
#pragma unroll 2
    for (int kk = 0; kk < 32; ++kk) {
      short8 xv = *(const short8*)(xplane + (((size_t)w * 32 + kk) * 64 + lane) * 8);
      aIr = mfma16(*(const short8*)(Wfih + (((size_t)(0 * 32 + bx) * 32 + kk) * 64 + lane) * 8), xv, aIr);
      aIz = mfma16(*(const short8*)(Wfih + (((size_t)(32 + bx) * 32 + kk) * 64 + lane) * 8), xv, aIz);
      aIn = mfma16(*(const short8*)(Wfih + (((size_t)(64 + bx) * 32 + kk) * 64 + lane) * 8), xv, aIn);
    }
  }
  {
#pragma unroll 2
    for (int kk = 0; kk < 16; ++kk) {
      short8 hv = *(const short8*)(hsold + (((size_t)w * 16 + kk) * 64 + lane) * 8);
      aHr = mfma16(*(const short8*)(Wfhh + (((size_t)(0 * 32 + bx) * 16 + kk) * 64 + lane) * 8), hv, aHr);
      aHz = mfma16(*(const short8*)(Wfhh + (((size_t)(32 + bx) * 16 + kk) * 64 + lane) * 8), hv, aHz);
      aHn = mfma16(*(const short8*)(Wfhh + (((size_t)(64 + bx) * 16 + kk) * 64 + lane) * 8), hv, aHn);
    }
  }
  int jb = bx * 16;
#pragma unroll
  for (int r = 0; r < 4; ++r) {
    int j = jb + 4 * g + r;
    int b = w * 16 + ln15;
    float ir = aIr[r] + bih[j];
    float iz = aIz[r] + bih[512 + j];
    float in_ = aIn[r] + bih[1024 + j];
    float hrv = aHr[r] + bhh[j];
    float hzv = aHz[r] + bhh[512 + j];
    float hnv = aHn[r] + bhh[1024 + j];
    float rg = 1.f / (1.f + __expf(-(ir + hrv)));
    float zg = 1.f / (1.f + __expf(-(iz + hzv)));
    float e2 = __expf(2.f * (in_ + rg * hnv));
    float ng = 1.f - 2.f / (e2 + 1.f);
    float ho = hTold[(size_t)j * B_ + b];
    float hv = (1.f - zg) * ng + zg * ho;
    hTnew[(size_t)j * B_ + b] = hv;
    hsnew[hsoff(b, j)] = f2b(hv);
  }
}

/* ---------------- logits: single-pass GEMM (raw write + partials) ---------------- */

__global__ __launch_bounds__(256) void k_blog(const unsigned short* __restrict__ Wb,
                                              const float* __restrict__ bout,
                                              const unsigned short* __restrict__ hsAll,
                                              float* __restrict__ pm, float* __restrict__ ps,
                                              float* __restrict__ out) {
  __shared__ float tile[64][68];
  __shared__ float redm[64][4], reds[64][4];
  int tid = threadIdx.x;
  int w = tid >> 6, lane = tid & 63, ln15 = lane & 15, g = lane >> 4;
  int vcol = blockIdx.x * 64 + w * 16 + ln15;
  bool vok = vcol < V_;
  int vr = vok ? vcol : (V_ - 1);
  const unsigned short* brow = Wb + (size_t)vr * H_ + 8 * g;
  short8 wb[16];
#pragma unroll
  for (int kk = 0; kk < 16; ++kk) wb[kk] = *(const short8*)(brow + kk * 32);
  float bo = bout[vr];
  int row = tid >> 2, seg = tid & 3;

  for (int t = 0; t < T_ - 1; ++t) {
    const unsigned short* hp = hsAll + (size_t)(t + 1) * BH;
#pragma unroll
    for (int mp = 0; mp < 2; ++mp) {
      f32x4 z4 = {0.f, 0.f, 0.f, 0.f};
      f32x4 acc0 = z4, acc1 = z4;
#pragma unroll
      for (int kk = 0; kk < 16; ++kk) {
        short8 a0 = *(const short8*)(hp + (((mp * 2 + 0) * 16 + kk) * 64 + lane) * 8);
        short8 a1 = *(const short8*)(hp + (((mp * 2 + 1) * 16 + kk) * 64 + lane) * 8);
        acc0 = mfma16(a0, wb[kk], acc0);
        acc1 = mfma16(a1, wb[kk], acc1);
      }
#pragma unroll
      for (int r = 0; r < 4; ++r) {
        int bi0 = (mp * 2 + 0) * 16 + 4 * g + r;
        int bi1 = (mp * 2 + 1) * 16 + 4 * g + r;
        tile[bi0][w * 16 + ln15] = vok ? acc0[r] + bo : -1e30f;
        tile[bi1][w * 16 + ln15] = vok ? acc1[r] + bo : -1e30f;
      }
    }
    __syncthreads();
    // raw stores (256B per row-segment group)
    {
      int cb = blockIdx.x * 64 + seg * 16;
      float* orow = out + ((size_t)row * T_ + (t + 1)) * V_ + cb;
      if (cb + 16 <= V_) {
#pragma unroll
        for (int q = 0; q < 4; ++q) {
          float4 v;
          v.x = tile[row][seg * 16 + q * 4 + 0];
          v.y = tile[row][seg * 16 + q * 4 + 1];
          v.z = tile[row][seg * 16 + q * 4 + 2];
          v.w = tile[row][seg * 16 + q * 4 + 3];
          *(float4*)(orow + q * 4) = v;
        }
      } else {
        for (int i = 0; i < 16; ++i)
          if (cb + i < V_) orow[i] = tile[row][seg * 16 + i];
      }
    }
    // partials
    float m = -1e30f;
#pragma unroll
    for (int i = 0; i < 16; ++i) m = fmaxf(m, tile[row][seg * 16 + i]);
    float s = 0.f;
#pragma unroll
    for (int i = 0; i < 16; ++i) s += __expf(tile[row][seg * 16 + i] - m);
    redm[row][seg] = m; reds[row][seg] = s;
    __syncthreads();
    if (seg == 0) {
      float m0 = redm[row][0], m1 = redm[row][1], m2 = redm[row][2], m3 = redm[row][3];
      float m4 = fmaxf(fmaxf(m0, m1), fmaxf(m2, m3));
      float s4 = reds[row][0] * __expf(m0 - m4) + reds[row][1] * __expf(m1 - m4) +
                 reds[row][2] * __expf(m2 - m4) + reds[row][3] * __expf(m3 - m4);
      size_t rho = (size_t)t * 64 + row;
      pm[rho * NBLK_LOG + blockIdx.x] = m4;
      ps[rho * NBLK_LOG + blockIdx.x] = s4;
    }
    __syncthreads();
  }
}

// merge partials -> lse[rho] ; grid 1280
__global__ __launch_bounds__(256) void k_lse(const float* __restrict__ pm,
                                             const float* __restrict__ ps,
                                             float* __restrict__ lse) {
  int rho = blockIdx.x;
  int tid = threadIdx.x;
  float m = -1e30f, s = 0.f;
  for (int p = tid; p < NBLK_LOG; p += 256) {
    float pmv = pm[(size_t)rho * NBLK_LOG + p], psv = ps[(size_t)rho * NBLK_LOG + p];
    float nm = fmaxf(m, pmv);
    s = s * __expf(m - nm) + psv * __expf(pmv - nm);
    m = nm;
  }
  __shared__ float lm[256], ls[256];
  lm[tid] = m; ls[tid] = s;
  __syncthreads();
  for (int o = 128; o > 0; o >>= 1) {
    if (tid < o) {
      float m2 = lm[tid + o], s2 = ls[tid + o];
      float nm = fmaxf(lm[tid], m2);
      ls[tid] = ls[tid] * __expf(lm[tid] - nm) + s2 * __expf(m2 - nm);
      lm[tid] = nm;
    }
    __syncthreads();
  }
  if (tid == 0) lse[rho] = lm[0] + logf(ls[0]);
}

// vectorized subtract ; grid 1280 (rho = t'*64 + b, plane t'+1)
__global__ __launch_bounds__(256) void k_fin(float* __restrict__ out, const float* __restrict__ lse) {
  int rho = blockIdx.x;
  int tp = rho >> 6, b = rho & 63;
  float Lv = lse[rho];
  float* o = out + ((size_t)b * T_ + (tp + 1)) * V_;
  float4* o4 = (float4*)o;
  int tid = threadIdx.x;
  for (int i = tid; i < 12564; i += 256) {
    float4 v = o4[i];
    v.x -= Lv; v.y -= Lv; v.z -= Lv; v.w -= Lv;
    o4[i] = v;
  }
  if (tid == 0) o[50256] -= Lv;
}

/* ---------------- host ---------------- */

extern "C" void kernel_launch(void* const* d_in, const int* in_sizes, int n_in,
                              void* d_out, int out_size, void* d_ws, size_t ws_size,
                              hipStream_t stream) {
  const float* enc   = (const float*)d_in[0];
  const float* dih   = (const float*)d_in[1];
  const float* mask  = (const float*)d_in[2];
  const float* et    = (const float*)d_in[4];
  const float* Wih   = (const float*)d_in[5];
  const float* Whh   = (const float*)d_in[6];
  const float* bih   = (const float*)d_in[7];
  const float* bhh   = (const float*)d_in[8];
  const float* Waenc = (const float*)d_in[9];
  const float* Wah   = (const float*)d_in[10];
  const float* vatt  = (const float*)d_in[11];
  const float* Wout  = (const float*)d_in[12];
  const float* bout  = (const float*)d_in[13];
  const int*   ref   = (const int*)d_in[14];
  float* out = (float*)d_out;

  char* w = (char*)d_ws;
  size_t o = 0;
  unsigned short* Wb    = (unsigned short*)(w + o); o += (size_t)V_ * H_ * 2;
  unsigned short* Wfih  = (unsigned short*)(w + o); o += (size_t)1536 * 1024 * 2;
  unsigned short* Wfhh  = (unsigned short*)(w + o); o += (size_t)1536 * 512 * 2;
  unsigned short* WaTb  = (unsigned short*)(w + o); o += (size_t)512 * 512 * 2;
  unsigned short* Wahf  = (unsigned short*)(w + o); o += (size_t)512 * 512 * 2;
  float* WahT32 = (float*)(w + o); o += (size_t)512 * 512 * 4;
  unsigned short* encb  = (unsigned short*)(w + o); o += (size_t)B_ * L_ * F_ * 2;
  unsigned short* epb   = (unsigned short*)(w + o); o += (size_t)B_ * L_ * A_ * 2;
  unsigned short* xAll  = (unsigned short*)(w + o); o += (size_t)20 * BD * 2;
  unsigned short* hsAll = (unsigned short*)(w + o); o += (size_t)T_ * BH * 2;
  float* hTAll = (float*)(w + o); o += (size_t)T_ * BH * 4;
  float* hw    = (float*)(w + o); o += (size_t)B_ * A_ * 4;
  float* scoreT = (float*)(w + o); o += (size_t)B_ * L_ * 4;
  float* pm  = (float*)(w + o); o += (size_t)NROW * NBLK_LOG * 4;
  float* ps  = (float*)(w + o); o += (size_t)NROW * NBLK_LOG * 4;
  float* lse = (float*)(w + o); o += (size_t)NROW * 4;

  k_cvt<<<4096, 256, 0, stream>>>(Wout, Wb, V_ * H_ / 4);
  k_cvt<<<2048, 256, 0, stream>>>(enc, encb, B_ * L_ * F_ / 4);
  k_wfrag<<<96, 256, 0, stream>>>(Wih, Wfih, 1024);
  k_wfrag<<<96, 256, 0, stream>>>(Whh, Wfhh, 512);
  k_transcvt<<<dim3(8, 8), 256, 0, stream>>>(Waenc, WaTb, 512, 512);
  k_trans32<<<dim3(8, 8), 256, 0, stream>>>(Wah, WahT32, 512, 512);
  k_wfrag<<<32, 256, 0, stream>>>(WahT32, Wahf, 512);
  k_trans32<<<dim3(8, 1), 256, 0, stream>>>(dih, hTAll, 64, 512);
  k_hs0<<<64, 256, 0, stream>>>(dih, hsAll);
  k_embAll<<<dim3(64, 20), 64, 0, stream>>>(ref, et, xAll);
  k_encproj2<<<200, 256, 0, stream>>>(encb, WaTb, epb);
  k_zero0<<<dim3(50, 64), 256, 0, stream>>>(out);

  for (int t = 0; t < T_ - 1; ++t) {
    const float* hT_t = hTAll + (size_t)t * BH;
    float* hT_n = hTAll + (size_t)(t + 1) * BH;
    const unsigned short* hs_t = hsAll + (size_t)t * BH;
    unsigned short* hs_n = hsAll + (size_t)(t + 1) * BH;
    unsigned short* xp = xAll + (size_t)t * BD;
    k_hw<<<32, 256, 0, stream>>>(Wahf, hs_t, hw);
    k_score<<<200, 256, 0, stream>>>(epb, hw, vatt, mask, scoreT);
    k_ctx<<<dim3(64, 4), 256, 0, stream>>>(scoreT, encb, xp);
    k_gruM<<<32, 256, 0, stream>>>(Wfih, Wfhh, bih, bhh, xp, hs_t, hT_t, hs_n, hT_n);
  }
  k_blog<<<NBLK_LOG, 256, 0, stream>>>(Wb, bout, hsAll, pm, ps, out);
  k_lse<<<1280, 256, 0, stream>>>(pm, ps, lse);
  k_fin<<<1280, 256, 0, stream>>>(out, lse);
}